// Round 15
// baseline (1338.669 us; speedup 1.0000x reference)
//
#include <hip/hip_runtime.h>
#include <hip/hip_bf16.h>

typedef unsigned short ushort_t;
typedef __attribute__((ext_vector_type(8))) short short8;   // 8 bf16 = 4 VGPRs
typedef __attribute__((ext_vector_type(4))) float f32x4;    // MFMA C/D

#define N_NODES 20000
#define N_EDGES 320000
#define F_NODE 64
#define F_EDGE 16
#define HID 300
#define HP 320          // padded hidden: row stride of h
#define NTILES 20       // wfrag n-tiles; tile 19 pure pad
#define DEPTH 3
#define N_GRAPHS 128
#define KE2N 384        // e2n K: 64 (x) + 300 (S) + 20 pad
#define ATS 328         // LDS A-tile row stride (ushorts); 656B rows, 16B-aligned

#define WFRAG_USHORT_PER_LAYER (10 * NTILES * 64 * 8)  // 102400 ushorts
#define W2FRAG_USHORT (NTILES * 64 * 8)                // 10240 ushorts (1 K-chunk)
#define WE2NFRAG_USHORT (12 * NTILES * 64 * 8)         // 122880 ushorts

__device__ __forceinline__ float bf2f(ushort_t u) {
    union { unsigned int i; float f; } v;
    v.i = ((unsigned int)u) << 16;
    return v.f;
}

// Packed f32x2 -> bf16x2 (gfx950 HW cvt if available; RNA fallback)
__device__ __forceinline__ unsigned int fpack(float lo, float hi) {
#if __has_builtin(__builtin_amdgcn_cvt_pk_bf16_f32)
    auto r = __builtin_amdgcn_cvt_pk_bf16_f32(lo, hi);
    union { decltype(r) b; unsigned int u; } v;
    v.b = r;
    return v.u;
#else
    union { float f; unsigned int i; } a, b;
    a.f = lo; b.f = hi;
    return ((a.i + 0x8000u) >> 16) | ((b.i + 0x8000u) & 0xffff0000u);
#endif
}
__device__ __forceinline__ ushort_t f2bf(float f) {
    return (ushort_t)(fpack(f, 0.f) & 0xffffu);
}

// ---------------- CSR build ----------------
__global__ __launch_bounds__(256) void csr_hist(
    const int* __restrict__ col, int* __restrict__ deg)
{
    int e = blockIdx.x * 256 + threadIdx.x;
    atomicAdd(&deg[col[e]], 1);
}

__global__ __launch_bounds__(256) void csr_scan(
    const int* __restrict__ deg, int* __restrict__ offsets,
    int* __restrict__ cursor)
{
    __shared__ int sums[256];
    const int t = threadIdx.x;
    const int CH = 79;
    int base = t * CH;
    int local = 0;
    for (int i = 0; i < CH; ++i) {
        int idx = base + i;
        if (idx < N_NODES) local += deg[idx];
    }
    sums[t] = local;
    __syncthreads();
    for (int off = 1; off < 256; off <<= 1) {
        int v = (t >= off) ? sums[t - off] : 0;
        __syncthreads();
        sums[t] += v;
        __syncthreads();
    }
    int run = (t > 0) ? sums[t - 1] : 0;
    for (int i = 0; i < CH; ++i) {
        int idx = base + i;
        if (idx < N_NODES) {
            offsets[idx] = run;
            cursor[idx] = run;
            run += deg[idx];
        }
    }
}

__global__ __launch_bounds__(256) void csr_fill(
    const int* __restrict__ col, int* __restrict__ cursor,
    int* __restrict__ eid)
{
    int e = blockIdx.x * 256 + threadIdx.x;
    int pos = atomicAdd(&cursor[col[e]], 1);
    eid[pos] = e;
}

__global__ __launch_bounds__(256) void ghist(
    const int* __restrict__ batch, int* __restrict__ gdeg)
{
    int n = blockIdx.x * 256 + threadIdx.x;
    if (n < N_NODES) atomicAdd(&gdeg[batch[n]], 1);
}

__global__ __launch_bounds__(128) void gscan(
    const int* __restrict__ gdeg, int* __restrict__ goff)
{
    __shared__ int s[128];
    int t = threadIdx.x;
    int d = gdeg[t];
    s[t] = d;
    __syncthreads();
    for (int off = 1; off < 128; off <<= 1) {
        int v = (t >= off) ? s[t - off] : 0;
        __syncthreads();
        s[t] += v;
        __syncthreads();
    }
    goff[t] = s[t] - d;
    if (t == 127) goff[128] = s[127];
}

// ---------------- W fragment pre-packs ----------------
__global__ __launch_bounds__(64) void wfrag_build(
    const float* __restrict__ W_convs, ushort_t* __restrict__ wfrag)
{
    const int c = blockIdx.x, t = blockIdx.y, l = blockIdx.z;
    const int lane = threadIdx.x;
    const int k0 = c * 32 + (lane >> 4) * 8;
    const int n  = t * 16 + (lane & 15);
    ushort_t* dst = wfrag + (size_t)l * WFRAG_USHORT_PER_LAYER
                  + ((size_t)(c * NTILES + t) * 64 + lane) * 8;
    const float* Wl = W_convs + (size_t)l * HID * HID;
    #pragma unroll
    for (int j = 0; j < 8; ++j) {
        int k = k0 + j;
        float v = (k < HID && n < HID) ? Wl[(long)k * HID + n] : 0.f;
        dst[j] = f2bf(v);
    }
}

__global__ __launch_bounds__(64) void wfrag2_build(
    const float* __restrict__ W_e2n, ushort_t* __restrict__ wfrag2)
{
    const int c = blockIdx.x, t = blockIdx.y;
    const int lane = threadIdx.x;
    const int k0 = c * 32 + (lane >> 4) * 8;
    const int n  = t * 16 + (lane & 15);
    ushort_t* dst = wfrag2 + ((size_t)(c * NTILES + t) * 64 + lane) * 8;
    #pragma unroll
    for (int j = 0; j < 8; ++j) {
        int k = k0 + j;
        float v = (k < F_NODE + HID && n < HID) ? W_e2n[(long)k * HID + n] : 0.f;
        dst[j] = f2bf(v);
    }
}

// W2 (= W_init rows 64..79) as ONE 16x16x32 B-chunk
__global__ __launch_bounds__(64) void w2frag_build(
    const float* __restrict__ W2, ushort_t* __restrict__ w2frag)
{
    const int t = blockIdx.x;
    const int lane = threadIdx.x;
    const int k0 = (lane >> 4) * 8;
    const int n  = t * 16 + (lane & 15);
    ushort_t* dst = w2frag + ((size_t)t * 64 + lane) * 8;
    #pragma unroll
    for (int j = 0; j < 8; ++j) {
        int k = k0 + j;
        float v = (k < F_EDGE && n < HID) ? W2[(long)k * HID + n] : 0.f;
        dst[j] = f2bf(v);
    }
}

// ---------------- kernels ----------------

// K1: xW1b[n][c] = bf16(b_init[c] + x[n] @ W_init[0:64]);  stride HID
__global__ __launch_bounds__(256) void node_init_gemm(
    const float* __restrict__ x, const float* __restrict__ W_init,
    const float* __restrict__ b_init, ushort_t* __restrict__ xW1b)
{
    __shared__ float xs[16 * 64];
    const int tid = threadIdx.x;
    const long n0 = (long)blockIdx.x * 16;
    for (int i = tid; i < 16 * 64; i += 256) xs[i] = x[n0 * 64 + i];
    __syncthreads();
    const int nl = tid >> 4, ct = tid & 15;
    for (int q = 0; q < 19; ++q) {
        int c = ct + 16 * q;
        if (c < HID) {
            float acc = b_init[c];
            #pragma unroll 8
            for (int k = 0; k < 64; ++k)
                acc = fmaf(xs[nl * 64 + k], W_init[(long)k * HID + c], acc);
            xW1b[(n0 + nl) * HID + c] = f2bf(acc);
        }
    }
}

// Fused conv layer, 32-edge blocks, 256 thr / 4 waves.
// phase 0: P = ea_tile @ W2 via MFMA -> LDS At.
// phase 1: edge update into At (pure loads + pk-cvt packing).
// phase 2: main MFMA; C staged back through At and stored as 16B coalesced
//          rows (was 40 scalar 2B stores/thread -> partial-line RMW + 8x
//          VMEM issue; now 5 wide stores/thread, full-line coverage).
// Cols 300..303 of C are exact zeros (wfrag pad) and are never read.
template<bool UPDATE>
__global__ __launch_bounds__(256) void fused_conv(
    ushort_t* h, const ushort_t* __restrict__ Sb,
    const ushort_t* __restrict__ xW1b, const float* __restrict__ edge_attr,
    const int* __restrict__ row, const ushort_t* __restrict__ w2frag,
    const ushort_t* __restrict__ wfrag_l)
{
    __shared__ ushort_t At[32 * ATS];   // 20992 B
    __shared__ int rows[32];
    const int tid = threadIdx.x;
    const int wave = tid >> 6, lane = tid & 63;
    const int quad = lane >> 4, m = lane & 15;
    const long e0 = (long)blockIdx.x * 32;
    if (tid < 32) rows[tid] = row[e0 + tid];

    // ---- phase 0: P = EA @ W2 ----
    {
        short8 a_ea[2];
        #pragma unroll
        for (int mt = 0; mt < 2; ++mt) {
            union { uint4 u4; short8 s8; } af;
            if (quad < 2) {
                const float* eap = edge_attr + (e0 + mt * 16 + m) * 16 + quad * 8;
                float4 v0 = *(const float4*)eap;
                float4 v1 = *(const float4*)(eap + 4);
                af.u4.x = fpack(v0.x, v0.y); af.u4.y = fpack(v0.z, v0.w);
                af.u4.z = fpack(v1.x, v1.y); af.u4.w = fpack(v1.z, v1.w);
            } else {
                af.u4.x = 0; af.u4.y = 0; af.u4.z = 0; af.u4.w = 0;
            }
            a_ea[mt] = af.s8;
        }
        const int nt0 = wave * 5;
        #pragma unroll
        for (int t = 0; t < 5; ++t) {
            short8 b = *(const short8*)(w2frag + ((size_t)(nt0 + t) * 64 + lane) * 8);
            #pragma unroll
            for (int mt = 0; mt < 2; ++mt) {
                f32x4 pc = (f32x4){0.f, 0.f, 0.f, 0.f};
                pc = __builtin_amdgcn_mfma_f32_16x16x32_bf16(a_ea[mt], b, pc, 0, 0, 0);
                int c = (nt0 + t) * 16 + m;
                #pragma unroll
                for (int r = 0; r < 4; ++r)
                    At[(mt * 16 + quad * 4 + r) * ATS + c] = f2bf(pc[r]);
            }
        }
    }
    __syncthreads();   // P complete (+ rows)

    // ---- phase 1: edge update into At ----
    for (int i = tid; i < 16 * 80; i += 256) {
        int p = i / 80, g = i % 80;
        int c0 = 4 * g;
        int la = 2 * p, lb = 2 * p + 1;
        uint2 oa, ob;
        if (g < 75) {
            long Ea = e0 + la, Eb = e0 + lb;
            int ra = rows[la], rb = rows[lb];
            ushort4 xa = *(const ushort4*)&xW1b[(long)ra * HID + c0];
            ushort4 xb = *(const ushort4*)&xW1b[(long)rb * HID + c0];
            ushort4 pa = *(const ushort4*)&At[la * ATS + c0];
            ushort4 pb = *(const ushort4*)&At[lb * ATS + c0];
            float h0a[4], h0b[4];
            h0a[0] = fmaxf(bf2f(xa.x) + bf2f(pa.x), 0.f);
            h0a[1] = fmaxf(bf2f(xa.y) + bf2f(pa.y), 0.f);
            h0a[2] = fmaxf(bf2f(xa.z) + bf2f(pa.z), 0.f);
            h0a[3] = fmaxf(bf2f(xa.w) + bf2f(pa.w), 0.f);
            h0b[0] = fmaxf(bf2f(xb.x) + bf2f(pb.x), 0.f);
            h0b[1] = fmaxf(bf2f(xb.y) + bf2f(pb.y), 0.f);
            h0b[2] = fmaxf(bf2f(xb.z) + bf2f(pb.z), 0.f);
            h0b[3] = fmaxf(bf2f(xb.w) + bf2f(pb.w), 0.f);
            if (UPDATE) {
                ushort4 wa = *(const ushort4*)&h[Ea * HP + c0];
                ushort4 wb = *(const ushort4*)&h[Eb * HP + c0];
                ushort4 sa = *(const ushort4*)&Sb[(long)ra * HID + c0];
                ushort4 sb = *(const ushort4*)&Sb[(long)rb * HID + c0];
                oa.x = fpack(fmaxf(bf2f(sa.x) - bf2f(wb.x) + h0a[0], 0.f),
                             fmaxf(bf2f(sa.y) - bf2f(wb.y) + h0a[1], 0.f));
                oa.y = fpack(fmaxf(bf2f(sa.z) - bf2f(wb.z) + h0a[2], 0.f),
                             fmaxf(bf2f(sa.w) - bf2f(wb.w) + h0a[3], 0.f));
                ob.x = fpack(fmaxf(bf2f(sb.x) - bf2f(wa.x) + h0b[0], 0.f),
                             fmaxf(bf2f(sb.y) - bf2f(wa.y) + h0b[1], 0.f));
                ob.y = fpack(fmaxf(bf2f(sb.z) - bf2f(wa.z) + h0b[2], 0.f),
                             fmaxf(bf2f(sb.w) - bf2f(wa.w) + h0b[3], 0.f));
            } else {
                oa.x = fpack(h0a[0], h0a[1]); oa.y = fpack(h0a[2], h0a[3]);
                ob.x = fpack(h0b[0], h0b[1]); ob.y = fpack(h0b[2], h0b[3]);
            }
        } else {
            oa.x = 0; oa.y = 0;   // K-pad cols 300..319
            ob = oa;
        }
        *(uint2*)&At[la * ATS + c0] = oa;
        *(uint2*)&At[lb * ATS + c0] = ob;
    }
    __syncthreads();   // A tile complete; all h reads done

    // ---- phase 2: main MFMA ----
    const int nt0 = wave * 5;
    f32x4 acc[5][2];
    #pragma unroll
    for (int t = 0; t < 5; ++t)
        #pragma unroll
        for (int mt = 0; mt < 2; ++mt)
            acc[t][mt] = (f32x4){0.f, 0.f, 0.f, 0.f};

    for (int c = 0; c < 10; ++c) {
        short8 a[2];
        #pragma unroll
        for (int mt = 0; mt < 2; ++mt)
            a[mt] = *(const short8*)&At[(mt * 16 + m) * ATS + c * 32 + quad * 8];
        #pragma unroll
        for (int t = 0; t < 5; ++t) {
            short8 b = *(const short8*)(wfrag_l
                + ((size_t)(c * NTILES + nt0 + t) * 64 + lane) * 8);
            #pragma unroll
            for (int mt = 0; mt < 2; ++mt)
                acc[t][mt] = __builtin_amdgcn_mfma_f32_16x16x32_bf16(
                    a[mt], b, acc[t][mt], 0, 0, 0);
        }
    }
    __syncthreads();   // all A-frag reads done; At is dead -> reuse for C

    // C -> LDS (2B writes), then wide coalesced stores (16B, full lines)
    #pragma unroll
    for (int t = 0; t < 5; ++t) {
        int col = (nt0 + t) * 16 + m;   // <= 319; cols 300..303 are zeros
        #pragma unroll
        for (int mt = 0; mt < 2; ++mt) {
            int rr = mt * 16 + quad * 4;
            #pragma unroll
            for (int r = 0; r < 4; ++r)
                At[(rr + r) * ATS + col] = f2bf(acc[t][mt][r]);
        }
    }
    __syncthreads();
    for (int i = tid; i < 32 * 38; i += 256) {   // 38 x 16B = 608B = cols 0..303
        int e = i / 38, q = i % 38;
        *(uint4*)&h[(e0 + e) * HP + q * 8] = *(const uint4*)&At[e * ATS + q * 8];
    }
}

// Final edge update: phase-0 P via MFMA, then in-place update.
__global__ __launch_bounds__(256) void edge_update_mfma(
    ushort_t* h, const ushort_t* __restrict__ Sb,
    const ushort_t* __restrict__ xW1b, const float* __restrict__ edge_attr,
    const int* __restrict__ row, const ushort_t* __restrict__ w2frag)
{
    __shared__ ushort_t Pt[32 * ATS];
    __shared__ int rows[32];
    const int tid = threadIdx.x;
    const int wave = tid >> 6, lane = tid & 63;
    const int quad = lane >> 4, m = lane & 15;
    const long e0 = (long)blockIdx.x * 32;
    if (tid < 32) rows[tid] = row[e0 + tid];

    {
        short8 a_ea[2];
        #pragma unroll
        for (int mt = 0; mt < 2; ++mt) {
            union { uint4 u4; short8 s8; } af;
            if (quad < 2) {
                const float* eap = edge_attr + (e0 + mt * 16 + m) * 16 + quad * 8;
                float4 v0 = *(const float4*)eap;
                float4 v1 = *(const float4*)(eap + 4);
                af.u4.x = fpack(v0.x, v0.y); af.u4.y = fpack(v0.z, v0.w);
                af.u4.z = fpack(v1.x, v1.y); af.u4.w = fpack(v1.z, v1.w);
            } else {
                af.u4.x = 0; af.u4.y = 0; af.u4.z = 0; af.u4.w = 0;
            }
            a_ea[mt] = af.s8;
        }
        const int nt0 = wave * 5;
        #pragma unroll
        for (int t = 0; t < 5; ++t) {
            short8 b = *(const short8*)(w2frag + ((size_t)(nt0 + t) * 64 + lane) * 8);
            #pragma unroll
            for (int mt = 0; mt < 2; ++mt) {
                f32x4 pc = (f32x4){0.f, 0.f, 0.f, 0.f};
                pc = __builtin_amdgcn_mfma_f32_16x16x32_bf16(a_ea[mt], b, pc, 0, 0, 0);
                int c = (nt0 + t) * 16 + m;
                #pragma unroll
                for (int r = 0; r < 4; ++r)
                    Pt[(mt * 16 + quad * 4 + r) * ATS + c] = f2bf(pc[r]);
            }
        }
    }
    __syncthreads();

    for (int i = tid; i < 16 * 75; i += 256) {
        int p = i / 75, g = i % 75;
        int c0 = 4 * g;
        int la = 2 * p, lb = 2 * p + 1;
        long Ea = e0 + la, Eb = e0 + lb;
        int ra = rows[la], rb = rows[lb];
        ushort4 wa = *(const ushort4*)&h[Ea * HP + c0];
        ushort4 wb = *(const ushort4*)&h[Eb * HP + c0];
        ushort4 sa = *(const ushort4*)&Sb[(long)ra * HID + c0];
        ushort4 sb = *(const ushort4*)&Sb[(long)rb * HID + c0];
        ushort4 xa = *(const ushort4*)&xW1b[(long)ra * HID + c0];
        ushort4 xb = *(const ushort4*)&xW1b[(long)rb * HID + c0];
        ushort4 pa = *(const ushort4*)&Pt[la * ATS + c0];
        ushort4 pb = *(const ushort4*)&Pt[lb * ATS + c0];
        float h0a[4], h0b[4];
        h0a[0] = fmaxf(bf2f(xa.x) + bf2f(pa.x), 0.f);
        h0a[1] = fmaxf(bf2f(xa.y) + bf2f(pa.y), 0.f);
        h0a[2] = fmaxf(bf2f(xa.z) + bf2f(pa.z), 0.f);
        h0a[3] = fmaxf(bf2f(xa.w) + bf2f(pa.w), 0.f);
        h0b[0] = fmaxf(bf2f(xb.x) + bf2f(pb.x), 0.f);
        h0b[1] = fmaxf(bf2f(xb.y) + bf2f(pb.y), 0.f);
        h0b[2] = fmaxf(bf2f(xb.z) + bf2f(pb.z), 0.f);
        h0b[3] = fmaxf(bf2f(xb.w) + bf2f(pb.w), 0.f);
        uint2 oa, ob;
        oa.x = fpack(fmaxf(bf2f(sa.x) - bf2f(wb.x) + h0a[0], 0.f),
                     fmaxf(bf2f(sa.y) - bf2f(wb.y) + h0a[1], 0.f));
        oa.y = fpack(fmaxf(bf2f(sa.z) - bf2f(wb.z) + h0a[2], 0.f),
                     fmaxf(bf2f(sa.w) - bf2f(wb.w) + h0a[3], 0.f));
        ob.x = fpack(fmaxf(bf2f(sb.x) - bf2f(wa.x) + h0b[0], 0.f),
                     fmaxf(bf2f(sb.y) - bf2f(wa.y) + h0b[1], 0.f));
        ob.y = fpack(fmaxf(bf2f(sb.z) - bf2f(wa.z) + h0b[2], 0.f),
                     fmaxf(bf2f(sb.w) - bf2f(wa.w) + h0b[3], 0.f));
        *(uint2*)&h[Ea * HP + c0] = oa;
        *(uint2*)&h[Eb * HP + c0] = ob;
    }
}

// K4: Sb[n][:] = bf16( bias[:] + segsum );  stride HID
__global__ __launch_bounds__(256) void gather_sum(
    const ushort_t* __restrict__ src, const int* __restrict__ offsets,
    const int* __restrict__ ends, const int* __restrict__ eid,
    const float* __restrict__ bias, ushort_t* __restrict__ Sb)
{
    long idx = (long)blockIdx.x * 256 + threadIdx.x;
    if (idx >= (long)N_NODES * 75) return;
    int n = (int)(idx / 75);
    int g = (int)(idx % 75);
    int beg = offsets[n], end = ends[n];
    float a0 = 0.f, a1 = 0.f, a2 = 0.f, a3 = 0.f;
    float b0 = 0.f, b1 = 0.f, b2 = 0.f, b3 = 0.f;
    int j = beg;
    for (; j + 1 < end; j += 2) {
        int e0i = eid[j], e1i = eid[j + 1];
        ushort4 v0 = ((const ushort4*)src)[(long)e0i * (HP / 4) + g];
        ushort4 v1 = ((const ushort4*)src)[(long)e1i * (HP / 4) + g];
        a0 += bf2f(v0.x); a1 += bf2f(v0.y); a2 += bf2f(v0.z); a3 += bf2f(v0.w);
        b0 += bf2f(v1.x); b1 += bf2f(v1.y); b2 += bf2f(v1.z); b3 += bf2f(v1.w);
    }
    if (j < end) {
        int e0i = eid[j];
        ushort4 v0 = ((const ushort4*)src)[(long)e0i * (HP / 4) + g];
        a0 += bf2f(v0.x); a1 += bf2f(v0.y); a2 += bf2f(v0.z); a3 += bf2f(v0.w);
    }
    float4 bv = *(const float4*)&bias[4 * g];
    uint2 o;
    o.x = fpack(a0 + b0 + bv.x, a1 + b1 + bv.y);
    o.y = fpack(a2 + b2 + bv.z, a3 + b3 + bv.w);
    *(uint2*)&Sb[(long)n * HID + 4 * g] = o;
}

// K4b: final gather -> bf16 into Ab cols 64..363
__global__ __launch_bounds__(256) void gather_ab(
    const ushort_t* __restrict__ src, const int* __restrict__ offsets,
    const int* __restrict__ ends, const int* __restrict__ eid,
    ushort_t* __restrict__ Ab)
{
    long idx = (long)blockIdx.x * 256 + threadIdx.x;
    if (idx >= (long)N_NODES * 75) return;
    int n = (int)(idx / 75);
    int g = (int)(idx % 75);
    int beg = offsets[n], end = ends[n];
    float a0 = 0.f, a1 = 0.f, a2 = 0.f, a3 = 0.f;
    float b0 = 0.f, b1 = 0.f, b2 = 0.f, b3 = 0.f;
    int j = beg;
    for (; j + 1 < end; j += 2) {
        int e0i = eid[j], e1i = eid[j + 1];
        ushort4 v0 = ((const ushort4*)src)[(long)e0i * (HP / 4) + g];
        ushort4 v1 = ((const ushort4*)src)[(long)e1i * (HP / 4) + g];
        a0 += bf2f(v0.x); a1 += bf2f(v0.y); a2 += bf2f(v0.z); a3 += bf2f(v0.w);
        b0 += bf2f(v1.x); b1 += bf2f(v1.y); b2 += bf2f(v1.z); b3 += bf2f(v1.w);
    }
    if (j < end) {
        int e0i = eid[j];
        ushort4 v0 = ((const ushort4*)src)[(long)e0i * (HP / 4) + g];
        a0 += bf2f(v0.x); a1 += bf2f(v0.y); a2 += bf2f(v0.z); a3 += bf2f(v0.w);
    }
    uint2 o;
    o.x = fpack(a0 + b0, a1 + b1);
    o.y = fpack(a2 + b2, a3 + b3);
    *(uint2*)&Ab[(long)n * KE2N + 64 + 4 * g] = o;
}

__global__ __launch_bounds__(256) void x_fill(
    const float* __restrict__ x, ushort_t* __restrict__ Ab)
{
    long idx = (long)blockIdx.x * 256 + threadIdx.x;
    if (idx >= (long)N_NODES * 21) return;
    int n = (int)(idx / 21);
    int q = (int)(idx % 21);
    if (q < 16) {
        float4 v = *(const float4*)&x[(long)n * 64 + 4 * q];
        uint2 o;
        o.x = fpack(v.x, v.y);
        o.y = fpack(v.z, v.w);
        *(uint2*)&Ab[(long)n * KE2N + 4 * q] = o;
    } else {
        uint2 o; o.x = 0; o.y = 0;
        *(uint2*)&Ab[(long)n * KE2N + 364 + 4 * (q - 16)] = o;
    }
}

// K7: hn = relu(Ab @ W_e2n + b)
__global__ __launch_bounds__(256) void e2n_mfma(
    const ushort_t* __restrict__ Ab, const ushort_t* __restrict__ wfrag2,
    const float* __restrict__ b_e2n, float* __restrict__ hn)
{
    const int tid = threadIdx.x;
    const int wave = tid >> 6, lane = tid & 63;
    const int quad = lane >> 4, m = lane & 15;
    const long n0 = (long)blockIdx.x * 64;
    const int nt0 = wave * 5;

    f32x4 acc[5][4];
    #pragma unroll
    for (int t = 0; t < 5; ++t)
        #pragma unroll
        for (int mt = 0; mt < 4; ++mt)
            acc[t][mt] = (f32x4){0.f, 0.f, 0.f, 0.f};

    for (int c = 0; c < 12; ++c) {
        short8 a[4];
        #pragma unroll
        for (int mt = 0; mt < 4; ++mt) {
            long r = n0 + mt * 16 + m;
            if (r > N_NODES - 1) r = N_NODES - 1;
            a[mt] = *(const short8*)(Ab + r * KE2N + c * 32 + quad * 8);
        }
        #pragma unroll
        for (int t = 0; t < 5; ++t) {
            short8 b = *(const short8*)(wfrag2
                + ((size_t)(c * NTILES + nt0 + t) * 64 + lane) * 8);
            #pragma unroll
            for (int mt = 0; mt < 4; ++mt)
                acc[t][mt] = __builtin_amdgcn_mfma_f32_16x16x32_bf16(
                    a[mt], b, acc[t][mt], 0, 0, 0);
        }
    }

    #pragma unroll
    for (int t = 0; t < 5; ++t) {
        int col = (nt0 + t) * 16 + m;
        if (col >= HID) continue;
        float bias = b_e2n[col];
        #pragma unroll
        for (int mt = 0; mt < 4; ++mt) {
            long rw = n0 + mt * 16 + quad * 4;
            #pragma unroll
            for (int r = 0; r < 4; ++r) {
                long rowi = rw + r;
                if (rowi < N_NODES)
                    hn[rowi * HP + col] = fmaxf(acc[t][mt][r] + bias, 0.f);
            }
        }
    }
}

__global__ __launch_bounds__(256) void pool_graph(
    const float* __restrict__ hn, const int* __restrict__ goff,
    float* __restrict__ pooled)
{
    int g = blockIdx.x;
    int beg = goff[g], end = goff[g + 1];
    for (int c = threadIdx.x; c < HID; c += 256) {
        float acc = 0.f;
        for (int n = beg; n < end; ++n)
            acc += hn[(long)n * HP + c];
        pooled[(long)g * HID + c] = acc;
    }
}

__global__ __launch_bounds__(64) void ffn_out(
    const float* __restrict__ pooled, const float* __restrict__ W_ffn,
    const float* __restrict__ b_ffn, float* __restrict__ out)
{
    int g = blockIdx.x;
    int lane = threadIdx.x;
    float s = 0.f;
    for (int c = lane; c < HID; c += 64)
        s += pooled[(long)g * HID + c] * W_ffn[c];
    #pragma unroll
    for (int off = 32; off > 0; off >>= 1)
        s += __shfl_down(s, off, 64);
    if (lane == 0) out[g] = s + b_ffn[0];
}

extern "C" void kernel_launch(void* const* d_in, const int* in_sizes, int n_in,
                              void* d_out, int out_size, void* d_ws, size_t ws_size,
                              hipStream_t stream) {
    const float* x         = (const float*)d_in[0];
    const float* edge_attr = (const float*)d_in[1];
    const int*   edge_index= (const int*)d_in[2];
    const int*   batch     = (const int*)d_in[3];
    const float* W_init    = (const float*)d_in[4];
    const float* b_init    = (const float*)d_in[5];
    const float* W_convs   = (const float*)d_in[6];
    const float* b_convs   = (const float*)d_in[7];
    const float* W_e2n     = (const float*)d_in[8];
    const float* b_e2n     = (const float*)d_in[9];
    const float* W_ffn     = (const float*)d_in[10];
    const float* b_ffn     = (const float*)d_in[11];
    float* out = (float*)d_out;

    const int* row = edge_index;
    const int* col = edge_index + N_EDGES;
    const float* W2 = W_init + (size_t)F_NODE * HID;

    // Workspace (~236 MB) — fits (ws known >= 255 MB)
    const size_t need = (size_t)N_EDGES * HP * 2
                      + (size_t)N_NODES * HID * 2
                      + (size_t)N_NODES * KE2N * 2
                      + (size_t)N_GRAPHS * HID * 4
                      + (size_t)N_NODES * 4 * 2 + (size_t)N_EDGES * 4
                      + (size_t)DEPTH * WFRAG_USHORT_PER_LAYER * 2
                      + (size_t)WE2NFRAG_USHORT * 2
                      + (size_t)W2FRAG_USHORT * 2
                      + (size_t)(N_GRAPHS + 1 + N_GRAPHS) * 4 + 32768;
    if (ws_size < need) return;

    char* p = (char*)d_ws;
    auto take = [&](size_t bytes) {
        char* q = p;
        p += (bytes + 255) & ~(size_t)255;
        return q;
    };
    ushort_t* h       = (ushort_t*)take((size_t)N_EDGES * HP * 2);
    ushort_t* Sb      = (ushort_t*)take((size_t)N_NODES * HID * 2);
    ushort_t* Ab      = (ushort_t*)take((size_t)N_NODES * KE2N * 2);
    float*    pooled  = (float*)take((size_t)N_GRAPHS * HID * 4);
    int*      cursor  = (int*)take((size_t)N_NODES * 4);
    int*      offsets = (int*)take((size_t)N_NODES * 4);
    int*      eid     = (int*)take((size_t)N_EDGES * 4);
    ushort_t* wfrag   = (ushort_t*)take((size_t)DEPTH * WFRAG_USHORT_PER_LAYER * 2);
    ushort_t* wfrag2  = (ushort_t*)take((size_t)WE2NFRAG_USHORT * 2);
    ushort_t* w2frag  = (ushort_t*)take((size_t)W2FRAG_USHORT * 2);
    int*      gdeg    = (int*)take((size_t)N_GRAPHS * 4);
    int*      goff    = (int*)take((size_t)(N_GRAPHS + 1) * 4);

    ushort_t* xW1b = Ab;        // alias: xW1b dead before x_fill writes Ab
    float*    hn   = (float*)h; // alias: h dead after gather_ab

    // CSR + graph-offset build
    hipMemsetAsync(cursor, 0, (size_t)N_NODES * 4, stream);
    hipMemsetAsync(gdeg, 0, (size_t)N_GRAPHS * 4, stream);
    csr_hist<<<N_EDGES / 256, 256, 0, stream>>>(col, cursor);
    csr_scan<<<1, 256, 0, stream>>>(cursor, offsets, cursor);
    csr_fill<<<N_EDGES / 256, 256, 0, stream>>>(col, cursor, eid);
    ghist<<<(N_NODES + 255) / 256, 256, 0, stream>>>(batch, gdeg);
    gscan<<<1, 128, 0, stream>>>(gdeg, goff);

    wfrag_build<<<dim3(10, NTILES, DEPTH), 64, 0, stream>>>(W_convs, wfrag);
    wfrag2_build<<<dim3(12, NTILES, 1), 64, 0, stream>>>(W_e2n, wfrag2);
    w2frag_build<<<NTILES, 64, 0, stream>>>(W2, w2frag);

    node_init_gemm<<<N_NODES / 16, 256, 0, stream>>>(x, W_init, b_init, xW1b);

    const int GS_GRID = ((N_NODES * 75) + 255) / 256;

    // layer 0
    fused_conv<false><<<N_EDGES / 32, 256, 0, stream>>>(
        h, Sb, xW1b, edge_attr, row, w2frag, wfrag);
    gather_sum<<<GS_GRID, 256, 0, stream>>>(
        h, offsets, cursor, eid, b_convs + 0 * HID, Sb);
    // layers 1,2
    fused_conv<true><<<N_EDGES / 32, 256, 0, stream>>>(
        h, Sb, xW1b, edge_attr, row, w2frag,
        wfrag + 1 * (size_t)WFRAG_USHORT_PER_LAYER);
    gather_sum<<<GS_GRID, 256, 0, stream>>>(
        h, offsets, cursor, eid, b_convs + 1 * HID, Sb);
    fused_conv<true><<<N_EDGES / 32, 256, 0, stream>>>(
        h, Sb, xW1b, edge_attr, row, w2frag,
        wfrag + 2 * (size_t)WFRAG_USHORT_PER_LAYER);
    gather_sum<<<GS_GRID, 256, 0, stream>>>(
        h, offsets, cursor, eid, b_convs + 2 * HID, Sb);
    // final update
    edge_update_mfma<<<N_EDGES / 32, 256, 0, stream>>>(
        h, Sb, xW1b, edge_attr, row, w2frag);

    // ---- e2n path ----
    x_fill<<<((N_NODES * 21) + 255) / 256, 256, 0, stream>>>(x, Ab);
    gather_ab<<<GS_GRID, 256, 0, stream>>>(h, offsets, cursor, eid, Ab);
    e2n_mfma<<<(N_NODES + 63) / 64, 256, 0, stream>>>(Ab, wfrag2, b_e2n, hn);
    pool_graph<<<N_GRAPHS, 256, 0, stream>>>(hn, goff, pooled);
    ffn_out<<<N_GRAPHS, 64, 0, stream>>>(pooled, W_ffn, b_ffn, out);
}

// Round 16
// 1246.162 us; speedup vs baseline: 1.0742x; 1.0742x over previous
//
#include <hip/hip_runtime.h>
#include <hip/hip_bf16.h>

typedef unsigned short ushort_t;
typedef __attribute__((ext_vector_type(8))) short short8;   // 8 bf16 = 4 VGPRs
typedef __attribute__((ext_vector_type(4))) float f32x4;    // MFMA C/D

#define N_NODES 20000
#define N_EDGES 320000
#define F_NODE 64
#define F_EDGE 16
#define HID 300
#define HS 304          // global h row stride (ushorts): 300 + 4, 16B-aligned rows
#define HP 320          // K-dim pad inside LDS tiles (10 chunks of 32); also hn stride
#define NTILES 20       // wfrag n-tiles; tile 19 pure pad
#define DEPTH 3
#define N_GRAPHS 128
#define KE2N 384        // e2n K: 64 (x) + 300 (S) + 20 pad
#define ATS 328         // LDS A-tile row stride (ushorts)

#define WFRAG_USHORT_PER_LAYER (10 * NTILES * 64 * 8)  // 102400 ushorts
#define W2FRAG_USHORT (NTILES * 64 * 8)                // 10240 ushorts (1 K-chunk)
#define WE2NFRAG_USHORT (12 * NTILES * 64 * 8)         // 122880 ushorts

__device__ __forceinline__ float bf2f(ushort_t u) {
    union { unsigned int i; float f; } v;
    v.i = ((unsigned int)u) << 16;
    return v.f;
}

// Packed f32x2 -> bf16x2 (gfx950 HW cvt if available; RNA fallback)
__device__ __forceinline__ unsigned int fpack(float lo, float hi) {
#if __has_builtin(__builtin_amdgcn_cvt_pk_bf16_f32)
    auto r = __builtin_amdgcn_cvt_pk_bf16_f32(lo, hi);
    union { decltype(r) b; unsigned int u; } v;
    v.b = r;
    return v.u;
#else
    union { float f; unsigned int i; } a, b;
    a.f = lo; b.f = hi;
    return ((a.i + 0x8000u) >> 16) | ((b.i + 0x8000u) & 0xffff0000u);
#endif
}
__device__ __forceinline__ ushort_t f2bf(float f) {
    return (ushort_t)(fpack(f, 0.f) & 0xffffu);
}

// ---------------- CSR build ----------------
__global__ __launch_bounds__(256) void csr_hist(
    const int* __restrict__ col, int* __restrict__ deg)
{
    int e = blockIdx.x * 256 + threadIdx.x;
    atomicAdd(&deg[col[e]], 1);
}

__global__ __launch_bounds__(256) void csr_scan(
    const int* __restrict__ deg, int* __restrict__ offsets,
    int* __restrict__ cursor)
{
    __shared__ int sums[256];
    const int t = threadIdx.x;
    const int CH = 79;
    int base = t * CH;
    int local = 0;
    for (int i = 0; i < CH; ++i) {
        int idx = base + i;
        if (idx < N_NODES) local += deg[idx];
    }
    sums[t] = local;
    __syncthreads();
    for (int off = 1; off < 256; off <<= 1) {
        int v = (t >= off) ? sums[t - off] : 0;
        __syncthreads();
        sums[t] += v;
        __syncthreads();
    }
    int run = (t > 0) ? sums[t - 1] : 0;
    for (int i = 0; i < CH; ++i) {
        int idx = base + i;
        if (idx < N_NODES) {
            offsets[idx] = run;
            cursor[idx] = run;
            run += deg[idx];
        }
    }
}

__global__ __launch_bounds__(256) void csr_fill(
    const int* __restrict__ col, int* __restrict__ cursor,
    int* __restrict__ eid)
{
    int e = blockIdx.x * 256 + threadIdx.x;
    int pos = atomicAdd(&cursor[col[e]], 1);
    eid[pos] = e;
}

__global__ __launch_bounds__(256) void ghist(
    const int* __restrict__ batch, int* __restrict__ gdeg)
{
    int n = blockIdx.x * 256 + threadIdx.x;
    if (n < N_NODES) atomicAdd(&gdeg[batch[n]], 1);
}

__global__ __launch_bounds__(128) void gscan(
    const int* __restrict__ gdeg, int* __restrict__ goff)
{
    __shared__ int s[128];
    int t = threadIdx.x;
    int d = gdeg[t];
    s[t] = d;
    __syncthreads();
    for (int off = 1; off < 128; off <<= 1) {
        int v = (t >= off) ? s[t - off] : 0;
        __syncthreads();
        s[t] += v;
        __syncthreads();
    }
    goff[t] = s[t] - d;
    if (t == 127) goff[128] = s[127];
}

// ---------------- W fragment pre-packs ----------------
__global__ __launch_bounds__(64) void wfrag_build(
    const float* __restrict__ W_convs, ushort_t* __restrict__ wfrag)
{
    const int c = blockIdx.x, t = blockIdx.y, l = blockIdx.z;
    const int lane = threadIdx.x;
    const int k0 = c * 32 + (lane >> 4) * 8;
    const int n  = t * 16 + (lane & 15);
    ushort_t* dst = wfrag + (size_t)l * WFRAG_USHORT_PER_LAYER
                  + ((size_t)(c * NTILES + t) * 64 + lane) * 8;
    const float* Wl = W_convs + (size_t)l * HID * HID;
    #pragma unroll
    for (int j = 0; j < 8; ++j) {
        int k = k0 + j;
        float v = (k < HID && n < HID) ? Wl[(long)k * HID + n] : 0.f;
        dst[j] = f2bf(v);
    }
}

__global__ __launch_bounds__(64) void wfrag2_build(
    const float* __restrict__ W_e2n, ushort_t* __restrict__ wfrag2)
{
    const int c = blockIdx.x, t = blockIdx.y;
    const int lane = threadIdx.x;
    const int k0 = c * 32 + (lane >> 4) * 8;
    const int n  = t * 16 + (lane & 15);
    ushort_t* dst = wfrag2 + ((size_t)(c * NTILES + t) * 64 + lane) * 8;
    #pragma unroll
    for (int j = 0; j < 8; ++j) {
        int k = k0 + j;
        float v = (k < F_NODE + HID && n < HID) ? W_e2n[(long)k * HID + n] : 0.f;
        dst[j] = f2bf(v);
    }
}

// W2 (= W_init rows 64..79) as ONE 16x16x32 B-chunk
__global__ __launch_bounds__(64) void w2frag_build(
    const float* __restrict__ W2, ushort_t* __restrict__ w2frag)
{
    const int t = blockIdx.x;
    const int lane = threadIdx.x;
    const int k0 = (lane >> 4) * 8;
    const int n  = t * 16 + (lane & 15);
    ushort_t* dst = w2frag + ((size_t)t * 64 + lane) * 8;
    #pragma unroll
    for (int j = 0; j < 8; ++j) {
        int k = k0 + j;
        float v = (k < F_EDGE && n < HID) ? W2[(long)k * HID + n] : 0.f;
        dst[j] = f2bf(v);
    }
}

// ---------------- kernels ----------------

// K1: xW1b[n][c] = bf16(b_init[c] + x[n] @ W_init[0:64]);  stride HID
__global__ __launch_bounds__(256) void node_init_gemm(
    const float* __restrict__ x, const float* __restrict__ W_init,
    const float* __restrict__ b_init, ushort_t* __restrict__ xW1b)
{
    __shared__ float xs[16 * 64];
    const int tid = threadIdx.x;
    const long n0 = (long)blockIdx.x * 16;
    for (int i = tid; i < 16 * 64; i += 256) xs[i] = x[n0 * 64 + i];
    __syncthreads();
    const int nl = tid >> 4, ct = tid & 15;
    for (int q = 0; q < 19; ++q) {
        int c = ct + 16 * q;
        if (c < HID) {
            float acc = b_init[c];
            #pragma unroll 8
            for (int k = 0; k < 64; ++k)
                acc = fmaf(xs[nl * 64 + k], W_init[(long)k * HID + c], acc);
            xW1b[(n0 + nl) * HID + c] = f2bf(acc);
        }
    }
}

// Fused conv layer, 32-edge blocks, 256 thr / 4 waves.  (R14 structure — the
// scalar C-stores were proven NOT to cause RMW fetch; LDS C-staging regressed.)
// phase 0: P = ea_tile @ W2 via MFMA -> LDS At.
// phase 1: edge update into At (pure loads + pk-cvt packing).
// phase 2: main MFMA h = A @ Wl (acc[5][2]); scalar 2B C-stores, stride HS.
template<bool UPDATE>
__global__ __launch_bounds__(256) void fused_conv(
    ushort_t* h, const ushort_t* __restrict__ Sb,
    const ushort_t* __restrict__ xW1b, const float* __restrict__ edge_attr,
    const int* __restrict__ row, const ushort_t* __restrict__ w2frag,
    const ushort_t* __restrict__ wfrag_l)
{
    __shared__ ushort_t At[32 * ATS];   // 20992 B
    __shared__ int rows[32];
    const int tid = threadIdx.x;
    const int wave = tid >> 6, lane = tid & 63;
    const int quad = lane >> 4, m = lane & 15;
    const long e0 = (long)blockIdx.x * 32;
    if (tid < 32) rows[tid] = row[e0 + tid];

    // ---- phase 0: P = EA @ W2 ----
    {
        short8 a_ea[2];
        #pragma unroll
        for (int mt = 0; mt < 2; ++mt) {
            union { uint4 u4; short8 s8; } af;
            if (quad < 2) {
                const float* eap = edge_attr + (e0 + mt * 16 + m) * 16 + quad * 8;
                float4 v0 = *(const float4*)eap;
                float4 v1 = *(const float4*)(eap + 4);
                af.u4.x = fpack(v0.x, v0.y); af.u4.y = fpack(v0.z, v0.w);
                af.u4.z = fpack(v1.x, v1.y); af.u4.w = fpack(v1.z, v1.w);
            } else {
                af.u4.x = 0; af.u4.y = 0; af.u4.z = 0; af.u4.w = 0;
            }
            a_ea[mt] = af.s8;
        }
        const int nt0 = wave * 5;
        #pragma unroll
        for (int t = 0; t < 5; ++t) {
            short8 b = *(const short8*)(w2frag + ((size_t)(nt0 + t) * 64 + lane) * 8);
            #pragma unroll
            for (int mt = 0; mt < 2; ++mt) {
                f32x4 pc = (f32x4){0.f, 0.f, 0.f, 0.f};
                pc = __builtin_amdgcn_mfma_f32_16x16x32_bf16(a_ea[mt], b, pc, 0, 0, 0);
                int c = (nt0 + t) * 16 + m;
                #pragma unroll
                for (int r = 0; r < 4; ++r)
                    At[(mt * 16 + quad * 4 + r) * ATS + c] = f2bf(pc[r]);
            }
        }
    }
    __syncthreads();   // P complete (+ rows)

    // ---- phase 1: edge update into At ----
    for (int i = tid; i < 16 * 80; i += 256) {
        int p = i / 80, g = i % 80;
        int c0 = 4 * g;
        int la = 2 * p, lb = 2 * p + 1;
        uint2 oa, ob;
        if (g < 75) {
            long Ea = e0 + la, Eb = e0 + lb;
            int ra = rows[la], rb = rows[lb];
            ushort4 xa = *(const ushort4*)&xW1b[(long)ra * HID + c0];
            ushort4 xb = *(const ushort4*)&xW1b[(long)rb * HID + c0];
            ushort4 pa = *(const ushort4*)&At[la * ATS + c0];
            ushort4 pb = *(const ushort4*)&At[lb * ATS + c0];
            float h0a[4], h0b[4];
            h0a[0] = fmaxf(bf2f(xa.x) + bf2f(pa.x), 0.f);
            h0a[1] = fmaxf(bf2f(xa.y) + bf2f(pa.y), 0.f);
            h0a[2] = fmaxf(bf2f(xa.z) + bf2f(pa.z), 0.f);
            h0a[3] = fmaxf(bf2f(xa.w) + bf2f(pa.w), 0.f);
            h0b[0] = fmaxf(bf2f(xb.x) + bf2f(pb.x), 0.f);
            h0b[1] = fmaxf(bf2f(xb.y) + bf2f(pb.y), 0.f);
            h0b[2] = fmaxf(bf2f(xb.z) + bf2f(pb.z), 0.f);
            h0b[3] = fmaxf(bf2f(xb.w) + bf2f(pb.w), 0.f);
            if (UPDATE) {
                ushort4 wa = *(const ushort4*)&h[Ea * HS + c0];
                ushort4 wb = *(const ushort4*)&h[Eb * HS + c0];
                ushort4 sa = *(const ushort4*)&Sb[(long)ra * HID + c0];
                ushort4 sb = *(const ushort4*)&Sb[(long)rb * HID + c0];
                oa.x = fpack(fmaxf(bf2f(sa.x) - bf2f(wb.x) + h0a[0], 0.f),
                             fmaxf(bf2f(sa.y) - bf2f(wb.y) + h0a[1], 0.f));
                oa.y = fpack(fmaxf(bf2f(sa.z) - bf2f(wb.z) + h0a[2], 0.f),
                             fmaxf(bf2f(sa.w) - bf2f(wb.w) + h0a[3], 0.f));
                ob.x = fpack(fmaxf(bf2f(sb.x) - bf2f(wa.x) + h0b[0], 0.f),
                             fmaxf(bf2f(sb.y) - bf2f(wa.y) + h0b[1], 0.f));
                ob.y = fpack(fmaxf(bf2f(sb.z) - bf2f(wa.z) + h0b[2], 0.f),
                             fmaxf(bf2f(sb.w) - bf2f(wa.w) + h0b[3], 0.f));
            } else {
                oa.x = fpack(h0a[0], h0a[1]); oa.y = fpack(h0a[2], h0a[3]);
                ob.x = fpack(h0b[0], h0b[1]); ob.y = fpack(h0b[2], h0b[3]);
            }
        } else {
            oa.x = 0; oa.y = 0;   // LDS K-pad cols 300..319
            ob = oa;
        }
        *(uint2*)&At[la * ATS + c0] = oa;
        *(uint2*)&At[lb * ATS + c0] = ob;
    }
    __syncthreads();   // A tile complete; all h reads done

    // ---- phase 2: main MFMA ----
    const int nt0 = wave * 5;
    f32x4 acc[5][2];
    #pragma unroll
    for (int t = 0; t < 5; ++t)
        #pragma unroll
        for (int mt = 0; mt < 2; ++mt)
            acc[t][mt] = (f32x4){0.f, 0.f, 0.f, 0.f};

    for (int c = 0; c < 10; ++c) {
        short8 a[2];
        #pragma unroll
        for (int mt = 0; mt < 2; ++mt)
            a[mt] = *(const short8*)&At[(mt * 16 + m) * ATS + c * 32 + quad * 8];
        #pragma unroll
        for (int t = 0; t < 5; ++t) {
            short8 b = *(const short8*)(wfrag_l
                + ((size_t)(c * NTILES + nt0 + t) * 64 + lane) * 8);
            #pragma unroll
            for (int mt = 0; mt < 2; ++mt)
                acc[t][mt] = __builtin_amdgcn_mfma_f32_16x16x32_bf16(
                    a[mt], b, acc[t][mt], 0, 0, 0);
        }
    }
    #pragma unroll
    for (int t = 0; t < 5; ++t) {
        int col = (nt0 + t) * 16 + m;
        if (col >= HID) continue;
        #pragma unroll
        for (int mt = 0; mt < 2; ++mt) {
            long rbase = (e0 + mt * 16 + quad * 4) * HS + col;
            #pragma unroll
            for (int r = 0; r < 4; ++r)
                h[rbase + (long)r * HS] = f2bf(acc[t][mt][r]);
        }
    }
}

// Final edge update: phase-0 P via MFMA, then in-place update (stride HS).
__global__ __launch_bounds__(256) void edge_update_mfma(
    ushort_t* h, const ushort_t* __restrict__ Sb,
    const ushort_t* __restrict__ xW1b, const float* __restrict__ edge_attr,
    const int* __restrict__ row, const ushort_t* __restrict__ w2frag)
{
    __shared__ ushort_t Pt[32 * ATS];
    __shared__ int rows[32];
    const int tid = threadIdx.x;
    const int wave = tid >> 6, lane = tid & 63;
    const int quad = lane >> 4, m = lane & 15;
    const long e0 = (long)blockIdx.x * 32;
    if (tid < 32) rows[tid] = row[e0 + tid];

    {
        short8 a_ea[2];
        #pragma unroll
        for (int mt = 0; mt < 2; ++mt) {
            union { uint4 u4; short8 s8; } af;
            if (quad < 2) {
                const float* eap = edge_attr + (e0 + mt * 16 + m) * 16 + quad * 8;
                float4 v0 = *(const float4*)eap;
                float4 v1 = *(const float4*)(eap + 4);
                af.u4.x = fpack(v0.x, v0.y); af.u4.y = fpack(v0.z, v0.w);
                af.u4.z = fpack(v1.x, v1.y); af.u4.w = fpack(v1.z, v1.w);
            } else {
                af.u4.x = 0; af.u4.y = 0; af.u4.z = 0; af.u4.w = 0;
            }
            a_ea[mt] = af.s8;
        }
        const int nt0 = wave * 5;
        #pragma unroll
        for (int t = 0; t < 5; ++t) {
            short8 b = *(const short8*)(w2frag + ((size_t)(nt0 + t) * 64 + lane) * 8);
            #pragma unroll
            for (int mt = 0; mt < 2; ++mt) {
                f32x4 pc = (f32x4){0.f, 0.f, 0.f, 0.f};
                pc = __builtin_amdgcn_mfma_f32_16x16x32_bf16(a_ea[mt], b, pc, 0, 0, 0);
                int c = (nt0 + t) * 16 + m;
                #pragma unroll
                for (int r = 0; r < 4; ++r)
                    Pt[(mt * 16 + quad * 4 + r) * ATS + c] = f2bf(pc[r]);
            }
        }
    }
    __syncthreads();

    for (int i = tid; i < 16 * 75; i += 256) {
        int p = i / 75, g = i % 75;
        int c0 = 4 * g;
        int la = 2 * p, lb = 2 * p + 1;
        long Ea = e0 + la, Eb = e0 + lb;
        int ra = rows[la], rb = rows[lb];
        ushort4 wa = *(const ushort4*)&h[Ea * HS + c0];
        ushort4 wb = *(const ushort4*)&h[Eb * HS + c0];
        ushort4 sa = *(const ushort4*)&Sb[(long)ra * HID + c0];
        ushort4 sb = *(const ushort4*)&Sb[(long)rb * HID + c0];
        ushort4 xa = *(const ushort4*)&xW1b[(long)ra * HID + c0];
        ushort4 xb = *(const ushort4*)&xW1b[(long)rb * HID + c0];
        ushort4 pa = *(const ushort4*)&Pt[la * ATS + c0];
        ushort4 pb = *(const ushort4*)&Pt[lb * ATS + c0];
        float h0a[4], h0b[4];
        h0a[0] = fmaxf(bf2f(xa.x) + bf2f(pa.x), 0.f);
        h0a[1] = fmaxf(bf2f(xa.y) + bf2f(pa.y), 0.f);
        h0a[2] = fmaxf(bf2f(xa.z) + bf2f(pa.z), 0.f);
        h0a[3] = fmaxf(bf2f(xa.w) + bf2f(pa.w), 0.f);
        h0b[0] = fmaxf(bf2f(xb.x) + bf2f(pb.x), 0.f);
        h0b[1] = fmaxf(bf2f(xb.y) + bf2f(pb.y), 0.f);
        h0b[2] = fmaxf(bf2f(xb.z) + bf2f(pb.z), 0.f);
        h0b[3] = fmaxf(bf2f(xb.w) + bf2f(pb.w), 0.f);
        uint2 oa, ob;
        oa.x = fpack(fmaxf(bf2f(sa.x) - bf2f(wb.x) + h0a[0], 0.f),
                     fmaxf(bf2f(sa.y) - bf2f(wb.y) + h0a[1], 0.f));
        oa.y = fpack(fmaxf(bf2f(sa.z) - bf2f(wb.z) + h0a[2], 0.f),
                     fmaxf(bf2f(sa.w) - bf2f(wb.w) + h0a[3], 0.f));
        ob.x = fpack(fmaxf(bf2f(sb.x) - bf2f(wa.x) + h0b[0], 0.f),
                     fmaxf(bf2f(sb.y) - bf2f(wa.y) + h0b[1], 0.f));
        ob.y = fpack(fmaxf(bf2f(sb.z) - bf2f(wa.z) + h0b[2], 0.f),
                     fmaxf(bf2f(sb.w) - bf2f(wa.w) + h0b[3], 0.f));
        *(uint2*)&h[Ea * HS + c0] = oa;
        *(uint2*)&h[Eb * HS + c0] = ob;
    }
}

// K4: Sb[n][:] = bf16( bias[:] + segsum );  src stride HS
__global__ __launch_bounds__(256) void gather_sum(
    const ushort_t* __restrict__ src, const int* __restrict__ offsets,
    const int* __restrict__ ends, const int* __restrict__ eid,
    const float* __restrict__ bias, ushort_t* __restrict__ Sb)
{
    long idx = (long)blockIdx.x * 256 + threadIdx.x;
    if (idx >= (long)N_NODES * 75) return;
    int n = (int)(idx / 75);
    int g = (int)(idx % 75);
    int beg = offsets[n], end = ends[n];
    float a0 = 0.f, a1 = 0.f, a2 = 0.f, a3 = 0.f;
    float b0 = 0.f, b1 = 0.f, b2 = 0.f, b3 = 0.f;
    int j = beg;
    for (; j + 1 < end; j += 2) {
        int e0i = eid[j], e1i = eid[j + 1];
        ushort4 v0 = ((const ushort4*)src)[(long)e0i * (HS / 4) + g];
        ushort4 v1 = ((const ushort4*)src)[(long)e1i * (HS / 4) + g];
        a0 += bf2f(v0.x); a1 += bf2f(v0.y); a2 += bf2f(v0.z); a3 += bf2f(v0.w);
        b0 += bf2f(v1.x); b1 += bf2f(v1.y); b2 += bf2f(v1.z); b3 += bf2f(v1.w);
    }
    if (j < end) {
        int e0i = eid[j];
        ushort4 v0 = ((const ushort4*)src)[(long)e0i * (HS / 4) + g];
        a0 += bf2f(v0.x); a1 += bf2f(v0.y); a2 += bf2f(v0.z); a3 += bf2f(v0.w);
    }
    float4 bv = *(const float4*)&bias[4 * g];
    uint2 o;
    o.x = fpack(a0 + b0 + bv.x, a1 + b1 + bv.y);
    o.y = fpack(a2 + b2 + bv.z, a3 + b3 + bv.w);
    *(uint2*)&Sb[(long)n * HID + 4 * g] = o;
}

// K4b: final gather -> bf16 into Ab cols 64..363;  src stride HS
__global__ __launch_bounds__(256) void gather_ab(
    const ushort_t* __restrict__ src, const int* __restrict__ offsets,
    const int* __restrict__ ends, const int* __restrict__ eid,
    ushort_t* __restrict__ Ab)
{
    long idx = (long)blockIdx.x * 256 + threadIdx.x;
    if (idx >= (long)N_NODES * 75) return;
    int n = (int)(idx / 75);
    int g = (int)(idx % 75);
    int beg = offsets[n], end = ends[n];
    float a0 = 0.f, a1 = 0.f, a2 = 0.f, a3 = 0.f;
    float b0 = 0.f, b1 = 0.f, b2 = 0.f, b3 = 0.f;
    int j = beg;
    for (; j + 1 < end; j += 2) {
        int e0i = eid[j], e1i = eid[j + 1];
        ushort4 v0 = ((const ushort4*)src)[(long)e0i * (HS / 4) + g];
        ushort4 v1 = ((const ushort4*)src)[(long)e1i * (HS / 4) + g];
        a0 += bf2f(v0.x); a1 += bf2f(v0.y); a2 += bf2f(v0.z); a3 += bf2f(v0.w);
        b0 += bf2f(v1.x); b1 += bf2f(v1.y); b2 += bf2f(v1.z); b3 += bf2f(v1.w);
    }
    if (j < end) {
        int e0i = eid[j];
        ushort4 v0 = ((const ushort4*)src)[(long)e0i * (HS / 4) + g];
        a0 += bf2f(v0.x); a1 += bf2f(v0.y); a2 += bf2f(v0.z); a3 += bf2f(v0.w);
    }
    uint2 o;
    o.x = fpack(a0 + b0, a1 + b1);
    o.y = fpack(a2 + b2, a3 + b3);
    *(uint2*)&Ab[(long)n * KE2N + 64 + 4 * g] = o;
}

__global__ __launch_bounds__(256) void x_fill(
    const float* __restrict__ x, ushort_t* __restrict__ Ab)
{
    long idx = (long)blockIdx.x * 256 + threadIdx.x;
    if (idx >= (long)N_NODES * 21) return;
    int n = (int)(idx / 21);
    int q = (int)(idx % 21);
    if (q < 16) {
        float4 v = *(const float4*)&x[(long)n * 64 + 4 * q];
        uint2 o;
        o.x = fpack(v.x, v.y);
        o.y = fpack(v.z, v.w);
        *(uint2*)&Ab[(long)n * KE2N + 4 * q] = o;
    } else {
        uint2 o; o.x = 0; o.y = 0;
        *(uint2*)&Ab[(long)n * KE2N + 364 + 4 * (q - 16)] = o;
    }
}

// K7: hn = relu(Ab @ W_e2n + b);  hn stride HP (fp32)
__global__ __launch_bounds__(256) void e2n_mfma(
    const ushort_t* __restrict__ Ab, const ushort_t* __restrict__ wfrag2,
    const float* __restrict__ b_e2n, float* __restrict__ hn)
{
    const int tid = threadIdx.x;
    const int wave = tid >> 6, lane = tid & 63;
    const int quad = lane >> 4, m = lane & 15;
    const long n0 = (long)blockIdx.x * 64;
    const int nt0 = wave * 5;

    f32x4 acc[5][4];
    #pragma unroll
    for (int t = 0; t < 5; ++t)
        #pragma unroll
        for (int mt = 0; mt < 4; ++mt)
            acc[t][mt] = (f32x4){0.f, 0.f, 0.f, 0.f};

    for (int c = 0; c < 12; ++c) {
        short8 a[4];
        #pragma unroll
        for (int mt = 0; mt < 4; ++mt) {
            long r = n0 + mt * 16 + m;
            if (r > N_NODES - 1) r = N_NODES - 1;
            a[mt] = *(const short8*)(Ab + r * KE2N + c * 32 + quad * 8);
        }
        #pragma unroll
        for (int t = 0; t < 5; ++t) {
            short8 b = *(const short8*)(wfrag2
                + ((size_t)(c * NTILES + nt0 + t) * 64 + lane) * 8);
            #pragma unroll
            for (int mt = 0; mt < 4; ++mt)
                acc[t][mt] = __builtin_amdgcn_mfma_f32_16x16x32_bf16(
                    a[mt], b, acc[t][mt], 0, 0, 0);
        }
    }

    #pragma unroll
    for (int t = 0; t < 5; ++t) {
        int col = (nt0 + t) * 16 + m;
        if (col >= HID) continue;
        float bias = b_e2n[col];
        #pragma unroll
        for (int mt = 0; mt < 4; ++mt) {
            long rw = n0 + mt * 16 + quad * 4;
            #pragma unroll
            for (int r = 0; r < 4; ++r) {
                long rowi = rw + r;
                if (rowi < N_NODES)
                    hn[rowi * HP + col] = fmaxf(acc[t][mt][r] + bias, 0.f);
            }
        }
    }
}

__global__ __launch_bounds__(256) void pool_graph(
    const float* __restrict__ hn, const int* __restrict__ goff,
    float* __restrict__ pooled)
{
    int g = blockIdx.x;
    int beg = goff[g], end = goff[g + 1];
    for (int c = threadIdx.x; c < HID; c += 256) {
        float acc = 0.f;
        for (int n = beg; n < end; ++n)
            acc += hn[(long)n * HP + c];
        pooled[(long)g * HID + c] = acc;
    }
}

__global__ __launch_bounds__(64) void ffn_out(
    const float* __restrict__ pooled, const float* __restrict__ W_ffn,
    const float* __restrict__ b_ffn, float* __restrict__ out)
{
    int g = blockIdx.x;
    int lane = threadIdx.x;
    float s = 0.f;
    for (int c = lane; c < HID; c += 64)
        s += pooled[(long)g * HID + c] * W_ffn[c];
    #pragma unroll
    for (int off = 32; off > 0; off >>= 1)
        s += __shfl_down(s, off, 64);
    if (lane == 0) out[g] = s + b_ffn[0];
}

extern "C" void kernel_launch(void* const* d_in, const int* in_sizes, int n_in,
                              void* d_out, int out_size, void* d_ws, size_t ws_size,
                              hipStream_t stream) {
    const float* x         = (const float*)d_in[0];
    const float* edge_attr = (const float*)d_in[1];
    const int*   edge_index= (const int*)d_in[2];
    const int*   batch     = (const int*)d_in[3];
    const float* W_init    = (const float*)d_in[4];
    const float* b_init    = (const float*)d_in[5];
    const float* W_convs   = (const float*)d_in[6];
    const float* b_convs   = (const float*)d_in[7];
    const float* W_e2n     = (const float*)d_in[8];
    const float* b_e2n     = (const float*)d_in[9];
    const float* W_ffn     = (const float*)d_in[10];
    const float* b_ffn     = (const float*)d_in[11];
    float* out = (float*)d_out;

    const int* row = edge_index;
    const int* col = edge_index + N_EDGES;
    const float* W2 = W_init + (size_t)F_NODE * HID;

    // Workspace (~226 MB): h 194.6M | Sb 12M | Ab 15.36M | misc
    const size_t SZ_H = (size_t)N_EDGES * HS * 2;   // 194.56 MB
    const size_t need = SZ_H
                      + (size_t)N_NODES * HID * 2
                      + (size_t)N_NODES * KE2N * 2
                      + (size_t)N_GRAPHS * HID * 4
                      + (size_t)N_NODES * 4 * 2 + (size_t)N_EDGES * 4
                      + (size_t)DEPTH * WFRAG_USHORT_PER_LAYER * 2
                      + (size_t)WE2NFRAG_USHORT * 2
                      + (size_t)W2FRAG_USHORT * 2
                      + (size_t)(N_GRAPHS + 1 + N_GRAPHS) * 4 + 32768;
    if (ws_size < need) return;

    char* p = (char*)d_ws;
    auto take = [&](size_t bytes) {
        char* q = p;
        p += (bytes + 255) & ~(size_t)255;
        return q;
    };
    ushort_t* h       = (ushort_t*)take(SZ_H);
    ushort_t* Sb      = (ushort_t*)take((size_t)N_NODES * HID * 2);
    ushort_t* Ab      = (ushort_t*)take((size_t)N_NODES * KE2N * 2);
    float*    pooled  = (float*)take((size_t)N_GRAPHS * HID * 4);
    int*      cursor  = (int*)take((size_t)N_NODES * 4);
    int*      offsets = (int*)take((size_t)N_NODES * 4);
    int*      eid     = (int*)take((size_t)N_EDGES * 4);
    ushort_t* wfrag   = (ushort_t*)take((size_t)DEPTH * WFRAG_USHORT_PER_LAYER * 2);
    ushort_t* wfrag2  = (ushort_t*)take((size_t)WE2NFRAG_USHORT * 2);
    ushort_t* w2frag  = (ushort_t*)take((size_t)W2FRAG_USHORT * 2);
    int*      gdeg    = (int*)take((size_t)N_GRAPHS * 4);
    int*      goff    = (int*)take((size_t)(N_GRAPHS + 1) * 4);

    ushort_t* xW1b = Ab;        // alias: xW1b dead before x_fill writes Ab
    float*    hn   = (float*)h; // alias: h dead after gather_ab (25.6MB < 194.6MB)

    // CSR + graph-offset build
    hipMemsetAsync(cursor, 0, (size_t)N_NODES * 4, stream);
    hipMemsetAsync(gdeg, 0, (size_t)N_GRAPHS * 4, stream);
    csr_hist<<<N_EDGES / 256, 256, 0, stream>>>(col, cursor);
    csr_scan<<<1, 256, 0, stream>>>(cursor, offsets, cursor);
    csr_fill<<<N_EDGES / 256, 256, 0, stream>>>(col, cursor, eid);
    ghist<<<(N_NODES + 255) / 256, 256, 0, stream>>>(batch, gdeg);
    gscan<<<1, 128, 0, stream>>>(gdeg, goff);

    wfrag_build<<<dim3(10, NTILES, DEPTH), 64, 0, stream>>>(W_convs, wfrag);
    wfrag2_build<<<dim3(12, NTILES, 1), 64, 0, stream>>>(W_e2n, wfrag2);
    w2frag_build<<<NTILES, 64, 0, stream>>>(W2, w2frag);

    node_init_gemm<<<N_NODES / 16, 256, 0, stream>>>(x, W_init, b_init, xW1b);

    const int GS_GRID = ((N_NODES * 75) + 255) / 256;

    // layer 0
    fused_conv<false><<<N_EDGES / 32, 256, 0, stream>>>(
        h, Sb, xW1b, edge_attr, row, w2frag, wfrag);
    gather_sum<<<GS_GRID, 256, 0, stream>>>(
        h, offsets, cursor, eid, b_convs + 0 * HID, Sb);
    // layers 1,2
    fused_conv<true><<<N_EDGES / 32, 256, 0, stream>>>(
        h, Sb, xW1b, edge_attr, row, w2frag,
        wfrag + 1 * (size_t)WFRAG_USHORT_PER_LAYER);
    gather_sum<<<GS_GRID, 256, 0, stream>>>(
        h, offsets, cursor, eid, b_convs + 1 * HID, Sb);
    fused_conv<true><<<N_EDGES / 32, 256, 0, stream>>>(
        h, Sb, xW1b, edge_attr, row, w2frag,
        wfrag + 2 * (size_t)WFRAG_USHORT_PER_LAYER);
    gather_sum<<<GS_GRID, 256, 0, stream>>>(
        h, offsets, cursor, eid, b_convs + 2 * HID, Sb);
    // final update
    edge_update_mfma<<<N_EDGES / 32, 256, 0, stream>>>(
        h, Sb, xW1b, edge_attr, row, w2frag);

    // ---- e2n path ----
    x_fill<<<((N_NODES * 21) + 255) / 256, 256, 0, stream>>>(x, Ab);
    gather_ab<<<GS_GRID, 256, 0, stream>>>(h, offsets, cursor, eid, Ab);
    e2n_mfma<<<(N_NODES + 63) / 64, 256, 0, stream>>>(Ab, wfrag2, b_e2n, hn);
    pool_graph<<<N_GRAPHS, 256, 0, stream>>>(hn, goff, pooled);
    ffn_out<<<N_GRAPHS, 64, 0, stream>>>(pooled, W_ffn, b_ffn, out);
}